// Round 8
// baseline (288.687 us; speedup 1.0000x reference)
//
#include <hip/hip_runtime.h>
#include <hip/hip_bf16.h>
#include <stdint.h>

// MultiHeadAttentionNoScale: B=2, L=2048, D=1024, H=16, dk=64.
// R14: attn q-tile 64 -> 128 via 4 waves/block, per-wave work UNCHANGED from
//      R6 (32 q-rows x 64 KV/tile, 36 MFMA, ps 32x72, ~96 VGPR). Mechanism:
//      K/V per bh re-staged by 16 blocks instead of 32 -> total stage+drain
//      events per CU halve; compute per barrier-region doubles (4x36 MFMA).
//      Deltas vs R6: barrier width 2->4 waves, blocks/CU 4->2, staging
//      chunks/wave 4->2. LDS = 16KB kv (Q staged through it) + 18KB ps =
//      34.8KB. Grid 32 bh x 16 qt = 512 blocks. Everything else = R13
//      (4 dispatches: prep incl. direct mask->rmb, qkv BK=64, ogemm).

typedef __bf16 bf16;
typedef __bf16 bf16x8 __attribute__((ext_vector_type(8)));
typedef float f32x4 __attribute__((ext_vector_type(4)));

#define AS1 __attribute__((address_space(1)))
#define AS3 __attribute__((address_space(3)))

__device__ __forceinline__ void g2l16(const void* g, void* l) {
    // async global->LDS, 16B per lane; LDS dest = wave-uniform base + lane*16
    __builtin_amdgcn_global_load_lds((AS1 void*)g, (AS3 void*)l, 16, 0, 0);
}

// true iff this lane's bit is set in wave-uniform mask m
__device__ __forceinline__ bool lane_masked(unsigned long long m) {
#if __has_builtin(__builtin_amdgcn_inverse_ballot_w64)
    return __builtin_amdgcn_inverse_ballot_w64(m);
#else
    return (m >> (threadIdx.x & 63)) & 1ull;
#endif
}

#define LOG2E 1.44269504088896f

// ---------------- prep: fp32->bf16 cvt (y=0..2) + W transpose (y=3) + mask->rmb (y=4) ----------------
// y=4: rmb word(task=qg*32+kt, r, nt): bit(lane) =
//   mask[qg*16 + (lane>>4)*4 + r][kt*64 + nt*16 + (lane&15)] != 0
__global__ __launch_bounds__(256) void prep_kernel(
    const float* __restrict__ q, const float* __restrict__ k, const float* __restrict__ v,
    bf16* xq, bf16* xk, bf16* xv,
    const float* W0, const float* W1, const float* W2, const float* W3,
    bf16* T0, bf16* T1, bf16* T2, bf16* T3,
    const unsigned int* __restrict__ mask, unsigned long long* __restrict__ rmb) {
    __shared__ __align__(16) bf16 t[64 * 72];   // [k][n], +8 pad (wtrans only)
    int y = blockIdx.y;
    int tid = threadIdx.x;
    if (y < 3) {
        const float* in = (y == 0) ? q : (y == 1) ? k : v;
        bf16* out = (y == 0) ? xq : (y == 1) ? xk : xv;
        int idx = blockIdx.x * 256 + tid;
        float4 vv = ((const float4*)in)[idx];
        __align__(8) bf16 o[4];
        o[0] = (bf16)vv.x; o[1] = (bf16)vv.y; o[2] = (bf16)vv.z; o[3] = (bf16)vv.w;
        *(uint2*)(out + (size_t)idx * 4) = *(const uint2*)o;
        return;
    }
    if (y == 4) {
        // mask -> rmb direct (one task per wave; 1024 blocks x 4 waves = 4096 tasks)
        int bx = blockIdx.x;
        if (bx >= 1024) return;
        int task = bx * 4 + (tid >> 6);            // 0..4095
        int qg = task >> 5, kt = task & 31;
        int lane = tid & 63, quad = lane >> 4, col = lane & 15;
        int row0 = qg * 16 + quad * 4;
        int c0 = kt * 64 + col;
        #pragma unroll
        for (int r = 0; r < 4; ++r) {
            const unsigned int* mrow = mask + (size_t)(row0 + r) * 2048;
            #pragma unroll
            for (int nt = 0; nt < 4; ++nt) {
                unsigned long long b = __ballot(mrow[c0 + nt * 16] != 0u);
                if (lane == 0) rmb[(size_t)task * 16 + r * 4 + nt] = b;
            }
        }
        return;
    }
    // y == 3: weight transpose
    int bx = blockIdx.x;
    if (bx >= 1024) return;
    const float* W; bf16* T;
    int wi = bx >> 8;
    if (wi == 0)      { W = W0; T = T0; }
    else if (wi == 1) { W = W1; T = T1; }
    else if (wi == 2) { W = W2; T = T2; }
    else              { W = W3; T = T3; }
    int x = bx & 255;
    int tx = x & 15, ty = x >> 4;
    int n0 = tx * 64, k0 = ty * 64;
    #pragma unroll
    for (int rr = 0; rr < 4; ++rr) {
        int idx = rr * 256 + tid;
        int r = idx >> 4, c4 = (idx & 15) * 4;
        float4 vv = *(const float4*)(W + (size_t)(k0 + r) * 1024 + n0 + c4);
        __align__(8) bf16 o[4];
        o[0] = (bf16)vv.x; o[1] = (bf16)vv.y; o[2] = (bf16)vv.z; o[3] = (bf16)vv.w;
        *(uint2*)&t[r * 72 + c4] = *(const uint2*)o;
    }
    __syncthreads();
    #pragma unroll
    for (int rr = 0; rr < 2; ++rr) {
        int idx = rr * 256 + tid;
        int n = idx >> 3, kc = (idx & 7) * 8;
        __align__(16) bf16 o[8];
        #pragma unroll
        for (int j = 0; j < 8; ++j) o[j] = t[(kc + j) * 72 + n];
        *(uint4*)(T + (size_t)(n0 + n) * 1024 + k0 + kc) = *(const uint4*)o;
    }
}

// ---------------- 128x128 bt-GEMM core, BK=64, XOR-swizzled LDS ----------------
// C[m,n] = (sum_k A[m,k]*Bt[n,k] + bias[n]) * scale
// MODE 0: bf16 head-layout [b][h][l][dk]; MODE 2: bf16 V^T [b][h][dk][l]
template <int MODE>
__device__ __forceinline__ void gemm128_core(const bf16* __restrict__ A,
                                             const bf16* __restrict__ Bt,
                                             const float* __restrict__ bias,
                                             void* __restrict__ Out, int bm, int bn,
                                             float scale) {
    __shared__ __align__(16) bf16 la[128 * 64];
    __shared__ __align__(16) bf16 lb[128 * 64];
    int tid = threadIdx.x;
    int w = tid >> 6, lane = tid & 63;
    int quad = lane >> 4, col = lane & 15;
    int c7 = col & 7;
    int wm = w >> 1, wn = w & 1;
    int m0 = bm * 128, n0 = bn * 128;
    f32x4 acc[4][4];
    f32x4 z = {0.f, 0.f, 0.f, 0.f};
    #pragma unroll
    for (int i = 0; i < 4; ++i)
        #pragma unroll
        for (int j = 0; j < 4; ++j) acc[i][j] = z;
    int sr = lane >> 3;              // row-within-chunk (8 rows/chunk)
    int sg = (lane & 7) ^ sr;        // swizzled 8-elem group this lane fetches
    int swz0 = (quad ^ c7) * 8;      // k2=0 fragment offset (elements)
    int swz1 = ((4 + quad) ^ c7) * 8;
    for (int kt = 0; kt < 16; ++kt) {
        int kk = kt * 64;
        __syncthreads();
        #pragma unroll
        for (int i = 0; i < 4; ++i) {
            int ch = w * 4 + i;          // 16 chunks of 8 rows
            int row = ch * 8 + sr;
            g2l16(A + (size_t)(m0 + row) * 1024 + kk + sg * 8, &la[ch * 512]);
            g2l16(Bt + (size_t)(n0 + row) * 1024 + kk + sg * 8, &lb[ch * 512]);
        }
        __syncthreads();
        bf16x8 af[4][2], bfr[4][2];
        #pragma unroll
        for (int mt = 0; mt < 4; ++mt) {
            af[mt][0] = *(const bf16x8*)&la[(wm * 64 + mt * 16 + col) * 64 + swz0];
            af[mt][1] = *(const bf16x8*)&la[(wm * 64 + mt * 16 + col) * 64 + swz1];
        }
        #pragma unroll
        for (int nt = 0; nt < 4; ++nt) {
            bfr[nt][0] = *(const bf16x8*)&lb[(wn * 64 + nt * 16 + col) * 64 + swz0];
            bfr[nt][1] = *(const bf16x8*)&lb[(wn * 64 + nt * 16 + col) * 64 + swz1];
        }
        #pragma unroll
        for (int mt = 0; mt < 4; ++mt)
            #pragma unroll
            for (int nt = 0; nt < 4; ++nt) {
                acc[mt][nt] = __builtin_amdgcn_mfma_f32_16x16x32_bf16(
                    af[mt][0], bfr[nt][0], acc[mt][nt], 0, 0, 0);
                acc[mt][nt] = __builtin_amdgcn_mfma_f32_16x16x32_bf16(
                    af[mt][1], bfr[nt][1], acc[mt][nt], 0, 0, 0);
            }
    }
    float bia[4];
    #pragma unroll
    for (int nt = 0; nt < 4; ++nt) bia[nt] = bias[n0 + wn * 64 + nt * 16 + col];
    #pragma unroll
    for (int mt = 0; mt < 4; ++mt) {
        #pragma unroll
        for (int nt = 0; nt < 4; ++nt) {
            #pragma unroll
            for (int r = 0; r < 4; ++r) {
                int m = m0 + wm * 64 + mt * 16 + quad * 4 + r;
                int n = n0 + wn * 64 + nt * 16 + col;
                float v = (acc[mt][nt][r] + bia[nt]) * scale;
                if (MODE == 0) {
                    int b = m >> 11, l = m & 2047, h = n >> 6, d = n & 63;
                    ((bf16*)Out)[(((size_t)b * 16 + h) * 2048 + l) * 64 + d] = (bf16)v;
                } else {
                    int b = m >> 11, l = m & 2047, h = n >> 6, d = n & 63;
                    ((bf16*)Out)[(((size_t)b * 16 + h) * 64 + d) * 2048 + l] = (bf16)v;
                }
            }
        }
    }
}

// Q scaled by log2e (folded softmax base conversion); K,V unscaled; V -> V^T layout
__global__ __launch_bounds__(256) void qkv_kernel(
    const bf16* Xq, const bf16* Xk, const bf16* Xv,
    const bf16* Wq, const bf16* Wk, const bf16* Wv,
    const float* bq, const float* bk, const float* bv,
    bf16* Qh, bf16* Kh, bf16* Vt) {
    int y = blockIdx.y;
    int bm = blockIdx.x >> 3, bn = blockIdx.x & 7;
    if (y == 0)      gemm128_core<0>(Xq, Wq, bq, Qh, bm, bn, LOG2E);
    else if (y == 1) gemm128_core<0>(Xk, Wk, bk, Kh, bm, bn, 1.0f);
    else             gemm128_core<2>(Xv, Wv, bv, Vt, bm, bn, 1.0f);
}

// ---------------- 64x128 GEMM for output projection, BK=64 (fp32 out) ----------------
__global__ __launch_bounds__(256) void ogemm_kernel(const bf16* __restrict__ A,
                                                    const bf16* __restrict__ Wt,
                                                    const float* __restrict__ bias,
                                                    float* __restrict__ Out) {
    int bm = blockIdx.x >> 3, bn = blockIdx.x & 7;   // 64 x 8 tiles
    __shared__ __align__(16) bf16 la[64 * 64];
    __shared__ __align__(16) bf16 lb[128 * 64];
    int tid = threadIdx.x;
    int w = tid >> 6, lane = tid & 63;
    int quad = lane >> 4, col = lane & 15;
    int c7 = col & 7;
    int m0 = bm * 64, n0 = bn * 128;
    f32x4 acc[4][2];
    f32x4 z = {0.f, 0.f, 0.f, 0.f};
    #pragma unroll
    for (int i = 0; i < 4; ++i) { acc[i][0] = z; acc[i][1] = z; }
    int sr = lane >> 3;
    int sg = (lane & 7) ^ sr;
    int swz0 = (quad ^ c7) * 8;
    int swz1 = ((4 + quad) ^ c7) * 8;
    for (int kt = 0; kt < 16; ++kt) {
        int kk = kt * 64;
        __syncthreads();
        #pragma unroll
        for (int i = 0; i < 2; ++i) {
            int ch = w * 2 + i;          // 8 chunks (64 rows)
            g2l16(A + (size_t)(m0 + ch * 8 + sr) * 1024 + kk + sg * 8, &la[ch * 512]);
        }
        #pragma unroll
        for (int i = 0; i < 4; ++i) {
            int ch = w * 4 + i;          // 16 chunks (128 rows)
            g2l16(Wt + (size_t)(n0 + ch * 8 + sr) * 1024 + kk + sg * 8, &lb[ch * 512]);
        }
        __syncthreads();
        bf16x8 af[4][2], bfr[2][2];
        #pragma unroll
        for (int mt = 0; mt < 4; ++mt) {
            af[mt][0] = *(const bf16x8*)&la[(mt * 16 + col) * 64 + swz0];
            af[mt][1] = *(const bf16x8*)&la[(mt * 16 + col) * 64 + swz1];
        }
        #pragma unroll
        for (int nt = 0; nt < 2; ++nt) {
            bfr[nt][0] = *(const bf16x8*)&lb[(w * 32 + nt * 16 + col) * 64 + swz0];
            bfr[nt][1] = *(const bf16x8*)&lb[(w * 32 + nt * 16 + col) * 64 + swz1];
        }
        #pragma unroll
        for (int mt = 0; mt < 4; ++mt)
            #pragma unroll
            for (int nt = 0; nt < 2; ++nt) {
                acc[mt][nt] = __builtin_amdgcn_mfma_f32_16x16x32_bf16(
                    af[mt][0], bfr[nt][0], acc[mt][nt], 0, 0, 0);
                acc[mt][nt] = __builtin_amdgcn_mfma_f32_16x16x32_bf16(
                    af[mt][1], bfr[nt][1], acc[mt][nt], 0, 0, 0);
            }
    }
    float bia[2];
    bia[0] = bias[n0 + w * 32 + col];
    bia[1] = bias[n0 + w * 32 + 16 + col];
    #pragma unroll
    for (int mt = 0; mt < 4; ++mt)
        #pragma unroll
        for (int nt = 0; nt < 2; ++nt)
            #pragma unroll
            for (int r = 0; r < 4; ++r)
                Out[(size_t)(m0 + mt * 16 + quad * 4 + r) * 1024 +
                    n0 + w * 32 + nt * 16 + col] = acc[mt][nt][r] + bia[nt];
}

// ---------------- flash attention: q-tile 128, 4 waves, R6 per-wave quantum ----------------
// Block = 256 threads (4 waves), q-tile 128 (wave w owns rows w*32..w*32+31).
// Grid 32 bh x 16 qt = 512 blocks = 2 blocks/CU (LDS 34816 B). Per tile:
// barrier; wave w stages K chunks w*2..w*2+1 and V chunks w*2..w*2+1 (16 KB
// total, half the per-wave issue of R6); barrier; then EXACTLY R6's per-wave
// compute (36 MFMA, exp2 softmax via rmb, ps 32x72 round-trip). K/V per bh is
// staged by 16 blocks instead of 32 -> total stage/drain events per CU halve.
__global__ __launch_bounds__(256) void attn_kernel(const bf16* __restrict__ Qh,
                                                   const bf16* __restrict__ Kh,
                                                   const bf16* __restrict__ Vt,
                                                   const unsigned long long* __restrict__ rmb,
                                                   bf16* __restrict__ att) {
    int bh = blockIdx.x, qt = blockIdx.y;
    int b = bh >> 4, h = bh & 15;
    int q0 = qt * 128;
    __shared__ __align__(16) bf16 kv[2 * 64 * 64];   // 16KB: K tile | V^T tile (Q staged thru both)
    __shared__ __align__(16) bf16 ps[4 * 32 * 72];   // per-wave P [qrow][j], +8 pad (18KB)
    int tid = threadIdx.x;
    int w = tid >> 6, lane = tid & 63;               // w in {0..3}
    int quad = lane >> 4, col = lane & 15;
    int c7 = col & 7;
    int sr = lane >> 3;              // row-within-chunk for staging (8 rows/chunk)
    int sg = (lane & 7) ^ sr;        // swizzled d-group this lane fetches
    int swz0 = (quad ^ c7) * 8;      // k2=0 fragment offset (elements)
    int swz1 = ((4 + quad) ^ c7) * 8;

    // mask word base for this wave's first 16-row group (wave-uniform -> s_loads)
    int mofs = __builtin_amdgcn_readfirstlane((qt * 8 + w * 2) * 512);

    // stage Q tile (128 rows = 16 chunks) through kv; wave w stages chunks w*4..w*4+3
    #pragma unroll
    for (int i = 0; i < 4; ++i) {
        int ch = w * 4 + i;
        g2l16(Qh + ((size_t)bh * 2048 + q0 + ch * 8 + sr) * 64 + sg * 8, &kv[ch * 512]);
    }
    __syncthreads();
    bf16x8 aq[2][2];
    #pragma unroll
    for (int mt = 0; mt < 2; ++mt) {
        aq[mt][0] = *(const bf16x8*)&kv[(w * 32 + mt * 16 + col) * 64 + swz0];
        aq[mt][1] = *(const bf16x8*)&kv[(w * 32 + mt * 16 + col) * 64 + swz1];
    }
    bf16x8 onesf;
    #pragma unroll
    for (int i = 0; i < 8; ++i) onesf[i] = (bf16)1.0f;

    f32x4 z = {0.f, 0.f, 0.f, 0.f};
    f32x4 O[2][4], R[2];
    #pragma unroll
    for (int mt = 0; mt < 2; ++mt) {
        R[mt] = z;
        #pragma unroll
        for (int i = 0; i < 4; ++i) O[mt][i] = z;
    }

    bf16* ks = &kv[0];
    bf16* vs = &kv[4096];
    for (int kt = 0; kt < 32; ++kt) {
        __syncthreads();   // (first iter: protects kv Q-reads before overwrite)
        #pragma unroll
        for (int i = 0; i < 2; ++i) {
            int ch = w * 2 + i;          // 8 chunks across 4 waves
            int r = ch * 8 + sr;
            g2l16(Kh + ((size_t)bh * 2048 + kt * 64 + r) * 64 + sg * 8, ks + ch * 512);
            g2l16(Vt + ((size_t)bh * 64 + r) * 2048 + kt * 64 + sg * 8, vs + ch * 512);
        }
        __syncthreads();

        // S = Q K^T : 32q x 64j per wave, each bk read feeds 2 MFMAs
        f32x4 s[2][4];
        #pragma unroll
        for (int nt = 0; nt < 4; ++nt) {
            s[0][nt] = z; s[1][nt] = z;
            bf16x8 bk0 = *(const bf16x8*)&ks[(nt * 16 + col) * 64 + swz0];
            s[0][nt] = __builtin_amdgcn_mfma_f32_16x16x32_bf16(aq[0][0], bk0, s[0][nt], 0, 0, 0);
            s[1][nt] = __builtin_amdgcn_mfma_f32_16x16x32_bf16(aq[1][0], bk0, s[1][nt], 0, 0, 0);
            bf16x8 bk1 = *(const bf16x8*)&ks[(nt * 16 + col) * 64 + swz1];
            s[0][nt] = __builtin_amdgcn_mfma_f32_16x16x32_bf16(aq[0][1], bk1, s[0][nt], 0, 0, 0);
            s[1][nt] = __builtin_amdgcn_mfma_f32_16x16x32_bf16(aq[1][1], bk1, s[1][nt], 0, 0, 0);
        }

        // p = exp2(s); zero masked lanes (1 cndmask per word); P -> per-wave LDS
        #pragma unroll
        for (int mt = 0; mt < 2; ++mt) {
            const unsigned long long* mw = rmb + mofs + mt * 512 + kt * 16;
            #pragma unroll
            for (int r = 0; r < 4; ++r) {
                #pragma unroll
                for (int nt = 0; nt < 4; ++nt) {
                    float p = __builtin_amdgcn_exp2f(s[mt][nt][r]);
                    if (lane_masked(mw[r * 4 + nt])) p = 0.0f;
                    ps[w * 2304 + (mt * 16 + quad * 4 + r) * 72 + nt * 16 + col] = (bf16)p;
                }
            }
        }

        // O += P V ; R += P * ones (row sums) — wave-synchronous ps round-trip
        bf16x8 ap[2][2];
        #pragma unroll
        for (int mt = 0; mt < 2; ++mt) {
            ap[mt][0] = *(const bf16x8*)&ps[w * 2304 + (mt * 16 + col) * 72 + quad * 8];
            ap[mt][1] = *(const bf16x8*)&ps[w * 2304 + (mt * 16 + col) * 72 + 32 + quad * 8];
        }
        #pragma unroll
        for (int dt = 0; dt < 4; ++dt) {
            bf16x8 bv0 = *(const bf16x8*)&vs[(dt * 16 + col) * 64 + swz0];
            O[0][dt] = __builtin_amdgcn_mfma_f32_16x16x32_bf16(ap[0][0], bv0, O[0][dt], 0, 0, 0);
            O[1][dt] = __builtin_amdgcn_mfma_f32_16x16x32_bf16(ap[1][0], bv0, O[1][dt], 0, 0, 0);
            bf16x8 bv1 = *(const bf16x8*)&vs[(dt * 16 + col) * 64 + swz1];
            O[0][dt] = __builtin_amdgcn_mfma_f32_16x16x32_bf16(ap[0][1], bv1, O[0][dt], 0, 0, 0);
            O[1][dt] = __builtin_amdgcn_mfma_f32_16x16x32_bf16(ap[1][1], bv1, O[1][dt], 0, 0, 0);
        }
        #pragma unroll
        for (int mt = 0; mt < 2; ++mt) {
            R[mt] = __builtin_amdgcn_mfma_f32_16x16x32_bf16(ap[mt][0], onesf, R[mt], 0, 0, 0);
            R[mt] = __builtin_amdgcn_mfma_f32_16x16x32_bf16(ap[mt][1], onesf, R[mt], 0, 0, 0);
        }
    }

    // epilogue: O/l, combined-head layout [b][l][h*64+d]; R holds row sums
    #pragma unroll
    for (int mt = 0; mt < 2; ++mt) {
        #pragma unroll
        for (int r = 0; r < 4; ++r) {
            float rsv = R[mt][r];
            float inv = (rsv > 0.f) ? 1.0f / rsv : 0.f;
            int qg = q0 + w * 32 + mt * 16 + quad * 4 + r;
            #pragma unroll
            for (int dt = 0; dt < 4; ++dt) {
                float ov = O[mt][dt][r] * inv;
                att[((size_t)b * 2048 + qg) * 1024 + h * 64 + dt * 16 + col] = (bf16)ov;
            }
        }
    }
}

extern "C" void kernel_launch(void* const* d_in, const int* in_sizes, int n_in,
                              void* d_out, int out_size, void* d_ws, size_t ws_size,
                              hipStream_t stream) {
    (void)in_sizes; (void)n_in; (void)out_size; (void)ws_size;
    const float* query = (const float*)d_in[0];
    const float* key_  = (const float*)d_in[1];
    const float* value = (const float*)d_in[2];
    const void*  mask  = d_in[3];
    const float* W_q = (const float*)d_in[4];
    const float* b_q = (const float*)d_in[5];
    const float* W_k = (const float*)d_in[6];
    const float* b_k = (const float*)d_in[7];
    const float* W_v = (const float*)d_in[8];
    const float* b_v = (const float*)d_in[9];
    const float* W_o = (const float*)d_in[10];
    const float* b_o = (const float*)d_in[11];

    char* ws = (char*)d_ws;
    bf16* Xq  = (bf16*)(ws + 0);
    bf16* Xk  = (bf16*)(ws + 8388608);
    bf16* Xv  = (bf16*)(ws + 16777216);
    bf16* Wtq = (bf16*)(ws + 25165824);
    bf16* Wtk = (bf16*)(ws + 27262976);
    bf16* Wtv = (bf16*)(ws + 29360128);
    bf16* Wto = (bf16*)(ws + 31457280);
    bf16* Qh  = (bf16*)(ws + 33554432);
    bf16* Kh  = (bf16*)(ws + 41943040);
    bf16* Vt  = (bf16*)(ws + 50331648);
    bf16* att = (bf16*)(ws + 58720256);
    unsigned long long* rmb = (unsigned long long*)(ws + 67633152);

    // prep: y=0..2 cvt fp32->bf16, y=3 W transpose, y=4 mask->rmb direct
    prep_kernel<<<dim3(4096, 5), 256, 0, stream>>>(query, key_, value, Xq, Xk, Xv,
                                                   W_q, W_k, W_v, W_o,
                                                   Wtq, Wtk, Wtv, Wto,
                                                   (const unsigned int*)mask, rmb);

    qkv_kernel<<<dim3(256, 3), 256, 0, stream>>>(Xq, Xk, Xv, Wtq, Wtk, Wtv,
                                                 b_q, b_k, b_v, Qh, Kh, Vt);
    attn_kernel<<<dim3(32, 16), 256, 0, stream>>>(Qh, Kh, Vt, rmb, att);
    ogemm_kernel<<<512, 256, 0, stream>>>(att, Wto, b_o, (float*)d_out);
}

// Round 9
// 281.240 us; speedup vs baseline: 1.0265x; 1.0265x over previous
//
#include <hip/hip_runtime.h>
#include <hip/hip_bf16.h>
#include <stdint.h>

// MultiHeadAttentionNoScale: B=2, L=2048, D=1024, H=16, dk=64.
// R15: attn reverted to R6 verbatim (the measured optimum across R6-R14:
//      occupancy map 8x1wave=96us < 4x2wave=78-84us > 2x4wave=94us) + T5
//      s_setprio(1) around the QK and PV/R MFMA clusters. Mechanism (m191):
//      4 independent blocks/CU at different loop phases -> priority keeps the
//      matrix pipe fed while other blocks' waves issue loads/exp2; null only
//      for lockstep barrier-synced waves (m190), which this is not.
//      Everything else = R13 (best total 266.5us): 4 dispatches, prep with
//      direct mask->rmb ballot, qkv/ogemm BK=64 swizzled.

typedef __bf16 bf16;
typedef __bf16 bf16x8 __attribute__((ext_vector_type(8)));
typedef float f32x4 __attribute__((ext_vector_type(4)));

#define AS1 __attribute__((address_space(1)))
#define AS3 __attribute__((address_space(3)))

__device__ __forceinline__ void g2l16(const void* g, void* l) {
    // async global->LDS, 16B per lane; LDS dest = wave-uniform base + lane*16
    __builtin_amdgcn_global_load_lds((AS1 void*)g, (AS3 void*)l, 16, 0, 0);
}

// true iff this lane's bit is set in wave-uniform mask m
__device__ __forceinline__ bool lane_masked(unsigned long long m) {
#if __has_builtin(__builtin_amdgcn_inverse_ballot_w64)
    return __builtin_amdgcn_inverse_ballot_w64(m);
#else
    return (m >> (threadIdx.x & 63)) & 1ull;
#endif
}

#define LOG2E 1.44269504088896f

// ---------------- prep: fp32->bf16 cvt (y=0..2) + W transpose (y=3) + mask->rmb (y=4) ----------------
// y=4: rmb word(task=qg*32+kt, r, nt): bit(lane) =
//   mask[qg*16 + (lane>>4)*4 + r][kt*64 + nt*16 + (lane&15)] != 0
__global__ __launch_bounds__(256) void prep_kernel(
    const float* __restrict__ q, const float* __restrict__ k, const float* __restrict__ v,
    bf16* xq, bf16* xk, bf16* xv,
    const float* W0, const float* W1, const float* W2, const float* W3,
    bf16* T0, bf16* T1, bf16* T2, bf16* T3,
    const unsigned int* __restrict__ mask, unsigned long long* __restrict__ rmb) {
    __shared__ __align__(16) bf16 t[64 * 72];   // [k][n], +8 pad (wtrans only)
    int y = blockIdx.y;
    int tid = threadIdx.x;
    if (y < 3) {
        const float* in = (y == 0) ? q : (y == 1) ? k : v;
        bf16* out = (y == 0) ? xq : (y == 1) ? xk : xv;
        int idx = blockIdx.x * 256 + tid;
        float4 vv = ((const float4*)in)[idx];
        __align__(8) bf16 o[4];
        o[0] = (bf16)vv.x; o[1] = (bf16)vv.y; o[2] = (bf16)vv.z; o[3] = (bf16)vv.w;
        *(uint2*)(out + (size_t)idx * 4) = *(const uint2*)o;
        return;
    }
    if (y == 4) {
        // mask -> rmb direct (one task per wave; 1024 blocks x 4 waves = 4096 tasks)
        int bx = blockIdx.x;
        if (bx >= 1024) return;
        int task = bx * 4 + (tid >> 6);            // 0..4095
        int qg = task >> 5, kt = task & 31;
        int lane = tid & 63, quad = lane >> 4, col = lane & 15;
        int row0 = qg * 16 + quad * 4;
        int c0 = kt * 64 + col;
        #pragma unroll
        for (int r = 0; r < 4; ++r) {
            const unsigned int* mrow = mask + (size_t)(row0 + r) * 2048;
            #pragma unroll
            for (int nt = 0; nt < 4; ++nt) {
                unsigned long long b = __ballot(mrow[c0 + nt * 16] != 0u);
                if (lane == 0) rmb[(size_t)task * 16 + r * 4 + nt] = b;
            }
        }
        return;
    }
    // y == 3: weight transpose
    int bx = blockIdx.x;
    if (bx >= 1024) return;
    const float* W; bf16* T;
    int wi = bx >> 8;
    if (wi == 0)      { W = W0; T = T0; }
    else if (wi == 1) { W = W1; T = T1; }
    else if (wi == 2) { W = W2; T = T2; }
    else              { W = W3; T = T3; }
    int x = bx & 255;
    int tx = x & 15, ty = x >> 4;
    int n0 = tx * 64, k0 = ty * 64;
    #pragma unroll
    for (int rr = 0; rr < 4; ++rr) {
        int idx = rr * 256 + tid;
        int r = idx >> 4, c4 = (idx & 15) * 4;
        float4 vv = *(const float4*)(W + (size_t)(k0 + r) * 1024 + n0 + c4);
        __align__(8) bf16 o[4];
        o[0] = (bf16)vv.x; o[1] = (bf16)vv.y; o[2] = (bf16)vv.z; o[3] = (bf16)vv.w;
        *(uint2*)&t[r * 72 + c4] = *(const uint2*)o;
    }
    __syncthreads();
    #pragma unroll
    for (int rr = 0; rr < 2; ++rr) {
        int idx = rr * 256 + tid;
        int n = idx >> 3, kc = (idx & 7) * 8;
        __align__(16) bf16 o[8];
        #pragma unroll
        for (int j = 0; j < 8; ++j) o[j] = t[(kc + j) * 72 + n];
        *(uint4*)(T + (size_t)(n0 + n) * 1024 + k0 + kc) = *(const uint4*)o;
    }
}

// ---------------- 128x128 bt-GEMM core, BK=64, XOR-swizzled LDS ----------------
// C[m,n] = (sum_k A[m,k]*Bt[n,k] + bias[n]) * scale
// MODE 0: bf16 head-layout [b][h][l][dk]; MODE 2: bf16 V^T [b][h][dk][l]
template <int MODE>
__device__ __forceinline__ void gemm128_core(const bf16* __restrict__ A,
                                             const bf16* __restrict__ Bt,
                                             const float* __restrict__ bias,
                                             void* __restrict__ Out, int bm, int bn,
                                             float scale) {
    __shared__ __align__(16) bf16 la[128 * 64];
    __shared__ __align__(16) bf16 lb[128 * 64];
    int tid = threadIdx.x;
    int w = tid >> 6, lane = tid & 63;
    int quad = lane >> 4, col = lane & 15;
    int c7 = col & 7;
    int wm = w >> 1, wn = w & 1;
    int m0 = bm * 128, n0 = bn * 128;
    f32x4 acc[4][4];
    f32x4 z = {0.f, 0.f, 0.f, 0.f};
    #pragma unroll
    for (int i = 0; i < 4; ++i)
        #pragma unroll
        for (int j = 0; j < 4; ++j) acc[i][j] = z;
    int sr = lane >> 3;              // row-within-chunk (8 rows/chunk)
    int sg = (lane & 7) ^ sr;        // swizzled 8-elem group this lane fetches
    int swz0 = (quad ^ c7) * 8;      // k2=0 fragment offset (elements)
    int swz1 = ((4 + quad) ^ c7) * 8;
    for (int kt = 0; kt < 16; ++kt) {
        int kk = kt * 64;
        __syncthreads();
        #pragma unroll
        for (int i = 0; i < 4; ++i) {
            int ch = w * 4 + i;          // 16 chunks of 8 rows
            int row = ch * 8 + sr;
            g2l16(A + (size_t)(m0 + row) * 1024 + kk + sg * 8, &la[ch * 512]);
            g2l16(Bt + (size_t)(n0 + row) * 1024 + kk + sg * 8, &lb[ch * 512]);
        }
        __syncthreads();
        bf16x8 af[4][2], bfr[4][2];
        #pragma unroll
        for (int mt = 0; mt < 4; ++mt) {
            af[mt][0] = *(const bf16x8*)&la[(wm * 64 + mt * 16 + col) * 64 + swz0];
            af[mt][1] = *(const bf16x8*)&la[(wm * 64 + mt * 16 + col) * 64 + swz1];
        }
        #pragma unroll
        for (int nt = 0; nt < 4; ++nt) {
            bfr[nt][0] = *(const bf16x8*)&lb[(wn * 64 + nt * 16 + col) * 64 + swz0];
            bfr[nt][1] = *(const bf16x8*)&lb[(wn * 64 + nt * 16 + col) * 64 + swz1];
        }
        #pragma unroll
        for (int mt = 0; mt < 4; ++mt)
            #pragma unroll
            for (int nt = 0; nt < 4; ++nt) {
                acc[mt][nt] = __builtin_amdgcn_mfma_f32_16x16x32_bf16(
                    af[mt][0], bfr[nt][0], acc[mt][nt], 0, 0, 0);
                acc[mt][nt] = __builtin_amdgcn_mfma_f32_16x16x32_bf16(
                    af[mt][1], bfr[nt][1], acc[mt][nt], 0, 0, 0);
            }
    }
    float bia[4];
    #pragma unroll
    for (int nt = 0; nt < 4; ++nt) bia[nt] = bias[n0 + wn * 64 + nt * 16 + col];
    #pragma unroll
    for (int mt = 0; mt < 4; ++mt) {
        #pragma unroll
        for (int nt = 0; nt < 4; ++nt) {
            #pragma unroll
            for (int r = 0; r < 4; ++r) {
                int m = m0 + wm * 64 + mt * 16 + quad * 4 + r;
                int n = n0 + wn * 64 + nt * 16 + col;
                float v = (acc[mt][nt][r] + bia[nt]) * scale;
                if (MODE == 0) {
                    int b = m >> 11, l = m & 2047, h = n >> 6, d = n & 63;
                    ((bf16*)Out)[(((size_t)b * 16 + h) * 2048 + l) * 64 + d] = (bf16)v;
                } else {
                    int b = m >> 11, l = m & 2047, h = n >> 6, d = n & 63;
                    ((bf16*)Out)[(((size_t)b * 16 + h) * 64 + d) * 2048 + l] = (bf16)v;
                }
            }
        }
    }
}

// Q scaled by log2e (folded softmax base conversion); K,V unscaled; V -> V^T layout
__global__ __launch_bounds__(256) void qkv_kernel(
    const bf16* Xq, const bf16* Xk, const bf16* Xv,
    const bf16* Wq, const bf16* Wk, const bf16* Wv,
    const float* bq, const float* bk, const float* bv,
    bf16* Qh, bf16* Kh, bf16* Vt) {
    int y = blockIdx.y;
    int bm = blockIdx.x >> 3, bn = blockIdx.x & 7;
    if (y == 0)      gemm128_core<0>(Xq, Wq, bq, Qh, bm, bn, LOG2E);
    else if (y == 1) gemm128_core<0>(Xk, Wk, bk, Kh, bm, bn, 1.0f);
    else             gemm128_core<2>(Xv, Wv, bv, Vt, bm, bn, 1.0f);
}

// ---------------- 64x128 GEMM for output projection, BK=64 (fp32 out) ----------------
__global__ __launch_bounds__(256) void ogemm_kernel(const bf16* __restrict__ A,
                                                    const bf16* __restrict__ Wt,
                                                    const float* __restrict__ bias,
                                                    float* __restrict__ Out) {
    int bm = blockIdx.x >> 3, bn = blockIdx.x & 7;   // 64 x 8 tiles
    __shared__ __align__(16) bf16 la[64 * 64];
    __shared__ __align__(16) bf16 lb[128 * 64];
    int tid = threadIdx.x;
    int w = tid >> 6, lane = tid & 63;
    int quad = lane >> 4, col = lane & 15;
    int c7 = col & 7;
    int m0 = bm * 64, n0 = bn * 128;
    f32x4 acc[4][2];
    f32x4 z = {0.f, 0.f, 0.f, 0.f};
    #pragma unroll
    for (int i = 0; i < 4; ++i) { acc[i][0] = z; acc[i][1] = z; }
    int sr = lane >> 3;
    int sg = (lane & 7) ^ sr;
    int swz0 = (quad ^ c7) * 8;
    int swz1 = ((4 + quad) ^ c7) * 8;
    for (int kt = 0; kt < 16; ++kt) {
        int kk = kt * 64;
        __syncthreads();
        #pragma unroll
        for (int i = 0; i < 2; ++i) {
            int ch = w * 2 + i;          // 8 chunks (64 rows)
            g2l16(A + (size_t)(m0 + ch * 8 + sr) * 1024 + kk + sg * 8, &la[ch * 512]);
        }
        #pragma unroll
        for (int i = 0; i < 4; ++i) {
            int ch = w * 4 + i;          // 16 chunks (128 rows)
            g2l16(Wt + (size_t)(n0 + ch * 8 + sr) * 1024 + kk + sg * 8, &lb[ch * 512]);
        }
        __syncthreads();
        bf16x8 af[4][2], bfr[2][2];
        #pragma unroll
        for (int mt = 0; mt < 4; ++mt) {
            af[mt][0] = *(const bf16x8*)&la[(mt * 16 + col) * 64 + swz0];
            af[mt][1] = *(const bf16x8*)&la[(mt * 16 + col) * 64 + swz1];
        }
        #pragma unroll
        for (int nt = 0; nt < 2; ++nt) {
            bfr[nt][0] = *(const bf16x8*)&lb[(w * 32 + nt * 16 + col) * 64 + swz0];
            bfr[nt][1] = *(const bf16x8*)&lb[(w * 32 + nt * 16 + col) * 64 + swz1];
        }
        #pragma unroll
        for (int mt = 0; mt < 4; ++mt)
            #pragma unroll
            for (int nt = 0; nt < 2; ++nt) {
                acc[mt][nt] = __builtin_amdgcn_mfma_f32_16x16x32_bf16(
                    af[mt][0], bfr[nt][0], acc[mt][nt], 0, 0, 0);
                acc[mt][nt] = __builtin_amdgcn_mfma_f32_16x16x32_bf16(
                    af[mt][1], bfr[nt][1], acc[mt][nt], 0, 0, 0);
            }
    }
    float bia[2];
    bia[0] = bias[n0 + w * 32 + col];
    bia[1] = bias[n0 + w * 32 + 16 + col];
    #pragma unroll
    for (int mt = 0; mt < 4; ++mt)
        #pragma unroll
        for (int nt = 0; nt < 2; ++nt)
            #pragma unroll
            for (int r = 0; r < 4; ++r)
                Out[(size_t)(m0 + mt * 16 + quad * 4 + r) * 1024 +
                    n0 + w * 32 + nt * 16 + col] = acc[mt][nt][r] + bia[nt];
}

// ---------------- flash attention (R6 structure + T5 setprio) ----------------
// Block = 128 threads (2 waves), q-tile 64 (32 q-rows/wave, mt in {0,1}).
// Grid 32 bh x 32 qt = 1024 blocks = 4 independent barrier domains per CU
// (measured optimum: 8x1wave and 2x4wave both regress). Q staged through ks.
// p = exp2(s) (log2e folded into Q projection). Mask: 1 cndmask per 64 elems
// via inverse_ballot of rmb words. Row sums: P x ones MFMA. Single-buffer
// 2-barrier K/V staging. NEW: s_setprio(1) around QK and PV/R MFMA clusters
// (T5/m191: pays when independent blocks per CU are at different phases).
__global__ __launch_bounds__(128) void attn_kernel(const bf16* __restrict__ Qh,
                                                   const bf16* __restrict__ Kh,
                                                   const bf16* __restrict__ Vt,
                                                   const unsigned long long* __restrict__ rmb,
                                                   bf16* __restrict__ att) {
    int bh = blockIdx.x, qt = blockIdx.y;
    int b = bh >> 4, h = bh & 15;
    int q0 = qt * 64;
    __shared__ __align__(16) bf16 ks[64 * 64];     // swizzled [row][g^(row&7)]; Q first
    __shared__ __align__(16) bf16 vs[64 * 64];     // V^T tile, rows = d
    __shared__ __align__(16) bf16 ps[2 * 32 * 72]; // per-wave P [qrow][j], +8 pad
    int tid = threadIdx.x;
    int w = tid >> 6, lane = tid & 63;             // w in {0,1}
    int quad = lane >> 4, col = lane & 15;
    int c7 = col & 7;
    int sr = lane >> 3;              // row-within-chunk for staging (8 rows/chunk)
    int sg = (lane & 7) ^ sr;        // swizzled d-group this lane fetches
    int swz0 = (quad ^ c7) * 8;      // k2=0 fragment offset (elements)
    int swz1 = ((4 + quad) ^ c7) * 8;

    // mask word base for this wave's first 16-row group (wave-uniform -> s_loads)
    int mofs = __builtin_amdgcn_readfirstlane((qt * 4 + w * 2) * 512);

    // stage Q tile (64 rows) through ks; wave w stages chunks w*4..w*4+3
    #pragma unroll
    for (int i = 0; i < 4; ++i) {
        int ch = w * 4 + i;
        g2l16(Qh + ((size_t)bh * 2048 + q0 + ch * 8 + sr) * 64 + sg * 8, &ks[ch * 512]);
    }
    __syncthreads();
    bf16x8 aq[2][2];
    #pragma unroll
    for (int mt = 0; mt < 2; ++mt) {
        aq[mt][0] = *(const bf16x8*)&ks[(w * 32 + mt * 16 + col) * 64 + swz0];
        aq[mt][1] = *(const bf16x8*)&ks[(w * 32 + mt * 16 + col) * 64 + swz1];
    }
    bf16x8 onesf;
    #pragma unroll
    for (int i = 0; i < 8; ++i) onesf[i] = (bf16)1.0f;

    f32x4 z = {0.f, 0.f, 0.f, 0.f};
    f32x4 O[2][4], R[2];
    #pragma unroll
    for (int mt = 0; mt < 2; ++mt) {
        R[mt] = z;
        #pragma unroll
        for (int i = 0; i < 4; ++i) O[mt][i] = z;
    }

    for (int kt = 0; kt < 32; ++kt) {
        __syncthreads();   // (first iter: protects ks Q-reads before overwrite)
        #pragma unroll
        for (int i = 0; i < 4; ++i) {
            int ch = w * 4 + i;
            int r = ch * 8 + sr;
            g2l16(Kh + ((size_t)bh * 2048 + kt * 64 + r) * 64 + sg * 8, &ks[ch * 512]);
            g2l16(Vt + ((size_t)bh * 64 + r) * 2048 + kt * 64 + sg * 8, &vs[ch * 512]);
        }
        __syncthreads();

        // S = Q K^T : 32q x 64j per wave, each bk read feeds 2 MFMAs
        f32x4 s[2][4];
        __builtin_amdgcn_s_setprio(1);
        #pragma unroll
        for (int nt = 0; nt < 4; ++nt) {
            s[0][nt] = z; s[1][nt] = z;
            bf16x8 bk0 = *(const bf16x8*)&ks[(nt * 16 + col) * 64 + swz0];
            s[0][nt] = __builtin_amdgcn_mfma_f32_16x16x32_bf16(aq[0][0], bk0, s[0][nt], 0, 0, 0);
            s[1][nt] = __builtin_amdgcn_mfma_f32_16x16x32_bf16(aq[1][0], bk0, s[1][nt], 0, 0, 0);
            bf16x8 bk1 = *(const bf16x8*)&ks[(nt * 16 + col) * 64 + swz1];
            s[0][nt] = __builtin_amdgcn_mfma_f32_16x16x32_bf16(aq[0][1], bk1, s[0][nt], 0, 0, 0);
            s[1][nt] = __builtin_amdgcn_mfma_f32_16x16x32_bf16(aq[1][1], bk1, s[1][nt], 0, 0, 0);
        }
        __builtin_amdgcn_s_setprio(0);

        // p = exp2(s); zero masked lanes (1 cndmask per word); P -> per-wave LDS
        #pragma unroll
        for (int mt = 0; mt < 2; ++mt) {
            const unsigned long long* mw = rmb + mofs + mt * 512 + kt * 16;
            #pragma unroll
            for (int r = 0; r < 4; ++r) {
                #pragma unroll
                for (int nt = 0; nt < 4; ++nt) {
                    float p = __builtin_amdgcn_exp2f(s[mt][nt][r]);
                    if (lane_masked(mw[r * 4 + nt])) p = 0.0f;
                    ps[w * 2304 + (mt * 16 + quad * 4 + r) * 72 + nt * 16 + col] = (bf16)p;
                }
            }
        }

        // O += P V ; R += P * ones (row sums) — wave-synchronous ps round-trip
        bf16x8 ap[2][2];
        #pragma unroll
        for (int mt = 0; mt < 2; ++mt) {
            ap[mt][0] = *(const bf16x8*)&ps[w * 2304 + (mt * 16 + col) * 72 + quad * 8];
            ap[mt][1] = *(const bf16x8*)&ps[w * 2304 + (mt * 16 + col) * 72 + 32 + quad * 8];
        }
        __builtin_amdgcn_s_setprio(1);
        #pragma unroll
        for (int dt = 0; dt < 4; ++dt) {
            bf16x8 bv0 = *(const bf16x8*)&vs[(dt * 16 + col) * 64 + swz0];
            O[0][dt] = __builtin_amdgcn_mfma_f32_16x16x32_bf16(ap[0][0], bv0, O[0][dt], 0, 0, 0);
            O[1][dt] = __builtin_amdgcn_mfma_f32_16x16x32_bf16(ap[1][0], bv0, O[1][dt], 0, 0, 0);
            bf16x8 bv1 = *(const bf16x8*)&vs[(dt * 16 + col) * 64 + swz1];
            O[0][dt] = __builtin_amdgcn_mfma_f32_16x16x32_bf16(ap[0][1], bv1, O[0][dt], 0, 0, 0);
            O[1][dt] = __builtin_amdgcn_mfma_f32_16x16x32_bf16(ap[1][1], bv1, O[1][dt], 0, 0, 0);
        }
        #pragma unroll
        for (int mt = 0; mt < 2; ++mt) {
            R[mt] = __builtin_amdgcn_mfma_f32_16x16x32_bf16(ap[mt][0], onesf, R[mt], 0, 0, 0);
            R[mt] = __builtin_amdgcn_mfma_f32_16x16x32_bf16(ap[mt][1], onesf, R[mt], 0, 0, 0);
        }
        __builtin_amdgcn_s_setprio(0);
    }

    // epilogue: O/l, combined-head layout [b][l][h*64+d]; R holds row sums
    #pragma unroll
    for (int mt = 0; mt < 2; ++mt) {
        #pragma unroll
        for (int r = 0; r < 4; ++r) {
            float rsv = R[mt][r];
            float inv = (rsv > 0.f) ? 1.0f / rsv : 0.f;
            int qg = q0 + w * 32 + mt * 16 + quad * 4 + r;
            #pragma unroll
            for (int dt = 0; dt < 4; ++dt) {
                float ov = O[mt][dt][r] * inv;
                att[((size_t)b * 2048 + qg) * 1024 + h * 64 + dt * 16 + col] = (bf16)ov;
            }
        }
    }
}

extern "C" void kernel_launch(void* const* d_in, const int* in_sizes, int n_in,
                              void* d_out, int out_size, void* d_ws, size_t ws_size,
                              hipStream_t stream) {
    (void)in_sizes; (void)n_in; (void)out_size; (void)ws_size;
    const float* query = (const float*)d_in[0];
    const float* key_  = (const float*)d_in[1];
    const float* value = (const float*)d_in[2];
    const void*  mask  = d_in[3];
    const float* W_q = (const float*)d_in[4];
    const float* b_q = (const float*)d_in[5];
    const float* W_k = (const float*)d_in[6];
    const float* b_k = (const float*)d_in[7];
    const float* W_v = (const float*)d_in[8];
    const float* b_v = (const float*)d_in[9];
    const float* W_o = (const float*)d_in[10];
    const float* b_o = (const float*)d_in[11];

    char* ws = (char*)d_ws;
    bf16* Xq  = (bf16*)(ws + 0);
    bf16* Xk  = (bf16*)(ws + 8388608);
    bf16* Xv  = (bf16*)(ws + 16777216);
    bf16* Wtq = (bf16*)(ws + 25165824);
    bf16* Wtk = (bf16*)(ws + 27262976);
    bf16* Wtv = (bf16*)(ws + 29360128);
    bf16* Wto = (bf16*)(ws + 31457280);
    bf16* Qh  = (bf16*)(ws + 33554432);
    bf16* Kh  = (bf16*)(ws + 41943040);
    bf16* Vt  = (bf16*)(ws + 50331648);
    bf16* att = (bf16*)(ws + 58720256);
    unsigned long long* rmb = (unsigned long long*)(ws + 67633152);

    // prep: y=0..2 cvt fp32->bf16, y=3 W transpose, y=4 mask->rmb direct
    prep_kernel<<<dim3(4096, 5), 256, 0, stream>>>(query, key_, value, Xq, Xk, Xv,
                                                   W_q, W_k, W_v, W_o,
                                                   Wtq, Wtk, Wtv, Wto,
                                                   (const unsigned int*)mask, rmb);

    qkv_kernel<<<dim3(256, 3), 256, 0, stream>>>(Xq, Xk, Xv, Wtq, Wtk, Wtv,
                                                 b_q, b_k, b_v, Qh, Kh, Vt);
    attn_kernel<<<dim3(32, 32), 128, 0, stream>>>(Qh, Kh, Vt, rmb, att);
    ogemm_kernel<<<512, 256, 0, stream>>>(att, Wto, b_o, (float*)d_out);
}

// Round 10
// 267.133 us; speedup vs baseline: 1.0807x; 1.0528x over previous
//
#include <hip/hip_runtime.h>
#include <hip/hip_bf16.h>
#include <stdint.h>

// MultiHeadAttentionNoScale: B=2, L=2048, D=1024, H=16, dk=64.
// R16: restore R13 exactly (best measured total: 266.5us) — R15's setprio
//      regressed attn via codegen perturbation (VGPR 96->76, less ILP).
//      Session evidence: 9 structural/scheduling variants of the attn loop
//      (R7-R12, R14, R15) all regressed vs the R6 structure; wins came from
//      pipeline-level changes (R13: 8->4 dispatches, direct mask->rmb).
//      One safe tweak vs R13: prep grid packed to (4096,4) — y=3 handles
//      wtrans (bx<1024) AND mask->rmb (1024<=bx<2048), removing 6144
//      empty-block launches. No kernel-body logic changed.

typedef __bf16 bf16;
typedef __bf16 bf16x8 __attribute__((ext_vector_type(8)));
typedef float f32x4 __attribute__((ext_vector_type(4)));

#define AS1 __attribute__((address_space(1)))
#define AS3 __attribute__((address_space(3)))

__device__ __forceinline__ void g2l16(const void* g, void* l) {
    // async global->LDS, 16B per lane; LDS dest = wave-uniform base + lane*16
    __builtin_amdgcn_global_load_lds((AS1 void*)g, (AS3 void*)l, 16, 0, 0);
}

// true iff this lane's bit is set in wave-uniform mask m
__device__ __forceinline__ bool lane_masked(unsigned long long m) {
#if __has_builtin(__builtin_amdgcn_inverse_ballot_w64)
    return __builtin_amdgcn_inverse_ballot_w64(m);
#else
    return (m >> (threadIdx.x & 63)) & 1ull;
#endif
}

#define LOG2E 1.44269504088896f

// ---------------- prep: fp32->bf16 cvt (y=0..2) + wtrans / mask->rmb (y=3) ----------------
// y=3, bx<1024: weight transpose; 1024<=bx<2048: rmb word(task=qg*32+kt, r, nt):
//   bit(lane) = mask[qg*16 + (lane>>4)*4 + r][kt*64 + nt*16 + (lane&15)] != 0
// (mask proven 4-byte elems: original mdetect read 16.8MB as words and passed;
//  int32 0/1 and fp32 0.0/1.0 both satisfy word!=0.)
__global__ __launch_bounds__(256) void prep_kernel(
    const float* __restrict__ q, const float* __restrict__ k, const float* __restrict__ v,
    bf16* xq, bf16* xk, bf16* xv,
    const float* W0, const float* W1, const float* W2, const float* W3,
    bf16* T0, bf16* T1, bf16* T2, bf16* T3,
    const unsigned int* __restrict__ mask, unsigned long long* __restrict__ rmb) {
    __shared__ __align__(16) bf16 t[64 * 72];   // [k][n], +8 pad (wtrans only)
    int y = blockIdx.y;
    int tid = threadIdx.x;
    if (y < 3) {
        const float* in = (y == 0) ? q : (y == 1) ? k : v;
        bf16* out = (y == 0) ? xq : (y == 1) ? xk : xv;
        int idx = blockIdx.x * 256 + tid;
        float4 vv = ((const float4*)in)[idx];
        __align__(8) bf16 o[4];
        o[0] = (bf16)vv.x; o[1] = (bf16)vv.y; o[2] = (bf16)vv.z; o[3] = (bf16)vv.w;
        *(uint2*)(out + (size_t)idx * 4) = *(const uint2*)o;
        return;
    }
    int bx = blockIdx.x;
    if (bx >= 2048) return;
    if (bx >= 1024) {
        // mask -> rmb direct (one task per wave; 1024 blocks x 4 waves = 4096 tasks)
        int task = (bx - 1024) * 4 + (tid >> 6);   // 0..4095
        int qg = task >> 5, kt = task & 31;
        int lane = tid & 63, quad = lane >> 4, col = lane & 15;
        int row0 = qg * 16 + quad * 4;
        int c0 = kt * 64 + col;
        #pragma unroll
        for (int r = 0; r < 4; ++r) {
            const unsigned int* mrow = mask + (size_t)(row0 + r) * 2048;
            #pragma unroll
            for (int nt = 0; nt < 4; ++nt) {
                unsigned long long b = __ballot(mrow[c0 + nt * 16] != 0u);
                if (lane == 0) rmb[(size_t)task * 16 + r * 4 + nt] = b;
            }
        }
        return;
    }
    // bx < 1024: weight transpose
    const float* W; bf16* T;
    int wi = bx >> 8;
    if (wi == 0)      { W = W0; T = T0; }
    else if (wi == 1) { W = W1; T = T1; }
    else if (wi == 2) { W = W2; T = T2; }
    else              { W = W3; T = T3; }
    int x = bx & 255;
    int tx = x & 15, ty = x >> 4;
    int n0 = tx * 64, k0 = ty * 64;
    #pragma unroll
    for (int rr = 0; rr < 4; ++rr) {
        int idx = rr * 256 + tid;
        int r = idx >> 4, c4 = (idx & 15) * 4;
        float4 vv = *(const float4*)(W + (size_t)(k0 + r) * 1024 + n0 + c4);
        __align__(8) bf16 o[4];
        o[0] = (bf16)vv.x; o[1] = (bf16)vv.y; o[2] = (bf16)vv.z; o[3] = (bf16)vv.w;
        *(uint2*)&t[r * 72 + c4] = *(const uint2*)o;
    }
    __syncthreads();
    #pragma unroll
    for (int rr = 0; rr < 2; ++rr) {
        int idx = rr * 256 + tid;
        int n = idx >> 3, kc = (idx & 7) * 8;
        __align__(16) bf16 o[8];
        #pragma unroll
        for (int j = 0; j < 8; ++j) o[j] = t[(kc + j) * 72 + n];
        *(uint4*)(T + (size_t)(n0 + n) * 1024 + k0 + kc) = *(const uint4*)o;
    }
}

// ---------------- 128x128 bt-GEMM core, BK=64, XOR-swizzled LDS ----------------
// C[m,n] = (sum_k A[m,k]*Bt[n,k] + bias[n]) * scale
// MODE 0: bf16 head-layout [b][h][l][dk]; MODE 2: bf16 V^T [b][h][dk][l]
template <int MODE>
__device__ __forceinline__ void gemm128_core(const bf16* __restrict__ A,
                                             const bf16* __restrict__ Bt,
                                             const float* __restrict__ bias,
                                             void* __restrict__ Out, int bm, int bn,
                                             float scale) {
    __shared__ __align__(16) bf16 la[128 * 64];
    __shared__ __align__(16) bf16 lb[128 * 64];
    int tid = threadIdx.x;
    int w = tid >> 6, lane = tid & 63;
    int quad = lane >> 4, col = lane & 15;
    int c7 = col & 7;
    int wm = w >> 1, wn = w & 1;
    int m0 = bm * 128, n0 = bn * 128;
    f32x4 acc[4][4];
    f32x4 z = {0.f, 0.f, 0.f, 0.f};
    #pragma unroll
    for (int i = 0; i < 4; ++i)
        #pragma unroll
        for (int j = 0; j < 4; ++j) acc[i][j] = z;
    int sr = lane >> 3;              // row-within-chunk (8 rows/chunk)
    int sg = (lane & 7) ^ sr;        // swizzled 8-elem group this lane fetches
    int swz0 = (quad ^ c7) * 8;      // k2=0 fragment offset (elements)
    int swz1 = ((4 + quad) ^ c7) * 8;
    for (int kt = 0; kt < 16; ++kt) {
        int kk = kt * 64;
        __syncthreads();
        #pragma unroll
        for (int i = 0; i < 4; ++i) {
            int ch = w * 4 + i;          // 16 chunks of 8 rows
            int row = ch * 8 + sr;
            g2l16(A + (size_t)(m0 + row) * 1024 + kk + sg * 8, &la[ch * 512]);
            g2l16(Bt + (size_t)(n0 + row) * 1024 + kk + sg * 8, &lb[ch * 512]);
        }
        __syncthreads();
        bf16x8 af[4][2], bfr[4][2];
        #pragma unroll
        for (int mt = 0; mt < 4; ++mt) {
            af[mt][0] = *(const bf16x8*)&la[(wm * 64 + mt * 16 + col) * 64 + swz0];
            af[mt][1] = *(const bf16x8*)&la[(wm * 64 + mt * 16 + col) * 64 + swz1];
        }
        #pragma unroll
        for (int nt = 0; nt < 4; ++nt) {
            bfr[nt][0] = *(const bf16x8*)&lb[(wn * 64 + nt * 16 + col) * 64 + swz0];
            bfr[nt][1] = *(const bf16x8*)&lb[(wn * 64 + nt * 16 + col) * 64 + swz1];
        }
        #pragma unroll
        for (int mt = 0; mt < 4; ++mt)
            #pragma unroll
            for (int nt = 0; nt < 4; ++nt) {
                acc[mt][nt] = __builtin_amdgcn_mfma_f32_16x16x32_bf16(
                    af[mt][0], bfr[nt][0], acc[mt][nt], 0, 0, 0);
                acc[mt][nt] = __builtin_amdgcn_mfma_f32_16x16x32_bf16(
                    af[mt][1], bfr[nt][1], acc[mt][nt], 0, 0, 0);
            }
    }
    float bia[4];
    #pragma unroll
    for (int nt = 0; nt < 4; ++nt) bia[nt] = bias[n0 + wn * 64 + nt * 16 + col];
    #pragma unroll
    for (int mt = 0; mt < 4; ++mt) {
        #pragma unroll
        for (int nt = 0; nt < 4; ++nt) {
            #pragma unroll
            for (int r = 0; r < 4; ++r) {
                int m = m0 + wm * 64 + mt * 16 + quad * 4 + r;
                int n = n0 + wn * 64 + nt * 16 + col;
                float v = (acc[mt][nt][r] + bia[nt]) * scale;
                if (MODE == 0) {
                    int b = m >> 11, l = m & 2047, h = n >> 6, d = n & 63;
                    ((bf16*)Out)[(((size_t)b * 16 + h) * 2048 + l) * 64 + d] = (bf16)v;
                } else {
                    int b = m >> 11, l = m & 2047, h = n >> 6, d = n & 63;
                    ((bf16*)Out)[(((size_t)b * 16 + h) * 64 + d) * 2048 + l] = (bf16)v;
                }
            }
        }
    }
}

// Q scaled by log2e (folded softmax base conversion); K,V unscaled; V -> V^T layout
__global__ __launch_bounds__(256) void qkv_kernel(
    const bf16* Xq, const bf16* Xk, const bf16* Xv,
    const bf16* Wq, const bf16* Wk, const bf16* Wv,
    const float* bq, const float* bk, const float* bv,
    bf16* Qh, bf16* Kh, bf16* Vt) {
    int y = blockIdx.y;
    int bm = blockIdx.x >> 3, bn = blockIdx.x & 7;
    if (y == 0)      gemm128_core<0>(Xq, Wq, bq, Qh, bm, bn, LOG2E);
    else if (y == 1) gemm128_core<0>(Xk, Wk, bk, Kh, bm, bn, 1.0f);
    else             gemm128_core<2>(Xv, Wv, bv, Vt, bm, bn, 1.0f);
}

// ---------------- 64x128 GEMM for output projection, BK=64 (fp32 out) ----------------
__global__ __launch_bounds__(256) void ogemm_kernel(const bf16* __restrict__ A,
                                                    const bf16* __restrict__ Wt,
                                                    const float* __restrict__ bias,
                                                    float* __restrict__ Out) {
    int bm = blockIdx.x >> 3, bn = blockIdx.x & 7;   // 64 x 8 tiles
    __shared__ __align__(16) bf16 la[64 * 64];
    __shared__ __align__(16) bf16 lb[128 * 64];
    int tid = threadIdx.x;
    int w = tid >> 6, lane = tid & 63;
    int quad = lane >> 4, col = lane & 15;
    int c7 = col & 7;
    int m0 = bm * 64, n0 = bn * 128;
    f32x4 acc[4][2];
    f32x4 z = {0.f, 0.f, 0.f, 0.f};
    #pragma unroll
    for (int i = 0; i < 4; ++i) { acc[i][0] = z; acc[i][1] = z; }
    int sr = lane >> 3;
    int sg = (lane & 7) ^ sr;
    int swz0 = (quad ^ c7) * 8;
    int swz1 = ((4 + quad) ^ c7) * 8;
    for (int kt = 0; kt < 16; ++kt) {
        int kk = kt * 64;
        __syncthreads();
        #pragma unroll
        for (int i = 0; i < 2; ++i) {
            int ch = w * 2 + i;          // 8 chunks (64 rows)
            g2l16(A + (size_t)(m0 + ch * 8 + sr) * 1024 + kk + sg * 8, &la[ch * 512]);
        }
        #pragma unroll
        for (int i = 0; i < 4; ++i) {
            int ch = w * 4 + i;          // 16 chunks (128 rows)
            g2l16(Wt + (size_t)(n0 + ch * 8 + sr) * 1024 + kk + sg * 8, &lb[ch * 512]);
        }
        __syncthreads();
        bf16x8 af[4][2], bfr[2][2];
        #pragma unroll
        for (int mt = 0; mt < 4; ++mt) {
            af[mt][0] = *(const bf16x8*)&la[(mt * 16 + col) * 64 + swz0];
            af[mt][1] = *(const bf16x8*)&la[(mt * 16 + col) * 64 + swz1];
        }
        #pragma unroll
        for (int nt = 0; nt < 2; ++nt) {
            bfr[nt][0] = *(const bf16x8*)&lb[(w * 32 + nt * 16 + col) * 64 + swz0];
            bfr[nt][1] = *(const bf16x8*)&lb[(w * 32 + nt * 16 + col) * 64 + swz1];
        }
        #pragma unroll
        for (int mt = 0; mt < 4; ++mt)
            #pragma unroll
            for (int nt = 0; nt < 2; ++nt) {
                acc[mt][nt] = __builtin_amdgcn_mfma_f32_16x16x32_bf16(
                    af[mt][0], bfr[nt][0], acc[mt][nt], 0, 0, 0);
                acc[mt][nt] = __builtin_amdgcn_mfma_f32_16x16x32_bf16(
                    af[mt][1], bfr[nt][1], acc[mt][nt], 0, 0, 0);
            }
    }
    float bia[2];
    bia[0] = bias[n0 + w * 32 + col];
    bia[1] = bias[n0 + w * 32 + 16 + col];
    #pragma unroll
    for (int mt = 0; mt < 4; ++mt)
        #pragma unroll
        for (int nt = 0; nt < 2; ++nt)
            #pragma unroll
            for (int r = 0; r < 4; ++r)
                Out[(size_t)(m0 + mt * 16 + quad * 4 + r) * 1024 +
                    n0 + w * 32 + nt * 16 + col] = acc[mt][nt][r] + bia[nt];
}

// ---------------- flash attention (R6, verbatim — measured optimum) ----------------
// Block = 128 threads (2 waves), q-tile 64 (32 q-rows/wave, mt in {0,1}).
// Grid 32 bh x 32 qt = 1024 blocks = 4 independent barrier domains per CU
// (occupancy map: 8x1wave=96us < 4x2wave=78-84us > 2x4wave=94us; dbuf,
// skew, direct-global, setprio all regressed). Q staged through ks.
// p = exp2(s) (log2e folded into Q projection). Mask: 1 cndmask per 64 elems
// via inverse_ballot of rmb words. Row sums: P x ones MFMA. Single-buffer
// 2-barrier K/V staging.
__global__ __launch_bounds__(128) void attn_kernel(const bf16* __restrict__ Qh,
                                                   const bf16* __restrict__ Kh,
                                                   const bf16* __restrict__ Vt,
                                                   const unsigned long long* __restrict__ rmb,
                                                   bf16* __restrict__ att) {
    int bh = blockIdx.x, qt = blockIdx.y;
    int b = bh >> 4, h = bh & 15;
    int q0 = qt * 64;
    __shared__ __align__(16) bf16 ks[64 * 64];     // swizzled [row][g^(row&7)]; Q first
    __shared__ __align__(16) bf16 vs[64 * 64];     // V^T tile, rows = d
    __shared__ __align__(16) bf16 ps[2 * 32 * 72]; // per-wave P [qrow][j], +8 pad
    int tid = threadIdx.x;
    int w = tid >> 6, lane = tid & 63;             // w in {0,1}
    int quad = lane >> 4, col = lane & 15;
    int c7 = col & 7;
    int sr = lane >> 3;              // row-within-chunk for staging (8 rows/chunk)
    int sg = (lane & 7) ^ sr;        // swizzled d-group this lane fetches
    int swz0 = (quad ^ c7) * 8;      // k2=0 fragment offset (elements)
    int swz1 = ((4 + quad) ^ c7) * 8;

    // mask word base for this wave's first 16-row group (wave-uniform -> s_loads)
    int mofs = __builtin_amdgcn_readfirstlane((qt * 4 + w * 2) * 512);

    // stage Q tile (64 rows) through ks; wave w stages chunks w*4..w*4+3
    #pragma unroll
    for (int i = 0; i < 4; ++i) {
        int ch = w * 4 + i;
        g2l16(Qh + ((size_t)bh * 2048 + q0 + ch * 8 + sr) * 64 + sg * 8, &ks[ch * 512]);
    }
    __syncthreads();
    bf16x8 aq[2][2];
    #pragma unroll
    for (int mt = 0; mt < 2; ++mt) {
        aq[mt][0] = *(const bf16x8*)&ks[(w * 32 + mt * 16 + col) * 64 + swz0];
        aq[mt][1] = *(const bf16x8*)&ks[(w * 32 + mt * 16 + col) * 64 + swz1];
    }
    bf16x8 onesf;
    #pragma unroll
    for (int i = 0; i < 8; ++i) onesf[i] = (bf16)1.0f;

    f32x4 z = {0.f, 0.f, 0.f, 0.f};
    f32x4 O[2][4], R[2];
    #pragma unroll
    for (int mt = 0; mt < 2; ++mt) {
        R[mt] = z;
        #pragma unroll
        for (int i = 0; i < 4; ++i) O[mt][i] = z;
    }

    for (int kt = 0; kt < 32; ++kt) {
        __syncthreads();   // (first iter: protects ks Q-reads before overwrite)
        #pragma unroll
        for (int i = 0; i < 4; ++i) {
            int ch = w * 4 + i;
            int r = ch * 8 + sr;
            g2l16(Kh + ((size_t)bh * 2048 + kt * 64 + r) * 64 + sg * 8, &ks[ch * 512]);
            g2l16(Vt + ((size_t)bh * 64 + r) * 2048 + kt * 64 + sg * 8, &vs[ch * 512]);
        }
        __syncthreads();

        // S = Q K^T : 32q x 64j per wave, each bk read feeds 2 MFMAs
        f32x4 s[2][4];
        #pragma unroll
        for (int nt = 0; nt < 4; ++nt) {
            s[0][nt] = z; s[1][nt] = z;
            bf16x8 bk0 = *(const bf16x8*)&ks[(nt * 16 + col) * 64 + swz0];
            s[0][nt] = __builtin_amdgcn_mfma_f32_16x16x32_bf16(aq[0][0], bk0, s[0][nt], 0, 0, 0);
            s[1][nt] = __builtin_amdgcn_mfma_f32_16x16x32_bf16(aq[1][0], bk0, s[1][nt], 0, 0, 0);
            bf16x8 bk1 = *(const bf16x8*)&ks[(nt * 16 + col) * 64 + swz1];
            s[0][nt] = __builtin_amdgcn_mfma_f32_16x16x32_bf16(aq[0][1], bk1, s[0][nt], 0, 0, 0);
            s[1][nt] = __builtin_amdgcn_mfma_f32_16x16x32_bf16(aq[1][1], bk1, s[1][nt], 0, 0, 0);
        }

        // p = exp2(s); zero masked lanes (1 cndmask per word); P -> per-wave LDS
        #pragma unroll
        for (int mt = 0; mt < 2; ++mt) {
            const unsigned long long* mw = rmb + mofs + mt * 512 + kt * 16;
            #pragma unroll
            for (int r = 0; r < 4; ++r) {
                #pragma unroll
                for (int nt = 0; nt < 4; ++nt) {
                    float p = __builtin_amdgcn_exp2f(s[mt][nt][r]);
                    if (lane_masked(mw[r * 4 + nt])) p = 0.0f;
                    ps[w * 2304 + (mt * 16 + quad * 4 + r) * 72 + nt * 16 + col] = (bf16)p;
                }
            }
        }

        // O += P V ; R += P * ones (row sums) — wave-synchronous ps round-trip
        bf16x8 ap[2][2];
        #pragma unroll
        for (int mt = 0; mt < 2; ++mt) {
            ap[mt][0] = *(const bf16x8*)&ps[w * 2304 + (mt * 16 + col) * 72 + quad * 8];
            ap[mt][1] = *(const bf16x8*)&ps[w * 2304 + (mt * 16 + col) * 72 + 32 + quad * 8];
        }
        #pragma unroll
        for (int dt = 0; dt < 4; ++dt) {
            bf16x8 bv0 = *(const bf16x8*)&vs[(dt * 16 + col) * 64 + swz0];
            O[0][dt] = __builtin_amdgcn_mfma_f32_16x16x32_bf16(ap[0][0], bv0, O[0][dt], 0, 0, 0);
            O[1][dt] = __builtin_amdgcn_mfma_f32_16x16x32_bf16(ap[1][0], bv0, O[1][dt], 0, 0, 0);
            bf16x8 bv1 = *(const bf16x8*)&vs[(dt * 16 + col) * 64 + swz1];
            O[0][dt] = __builtin_amdgcn_mfma_f32_16x16x32_bf16(ap[0][1], bv1, O[0][dt], 0, 0, 0);
            O[1][dt] = __builtin_amdgcn_mfma_f32_16x16x32_bf16(ap[1][1], bv1, O[1][dt], 0, 0, 0);
        }
        #pragma unroll
        for (int mt = 0; mt < 2; ++mt) {
            R[mt] = __builtin_amdgcn_mfma_f32_16x16x32_bf16(ap[mt][0], onesf, R[mt], 0, 0, 0);
            R[mt] = __builtin_amdgcn_mfma_f32_16x16x32_bf16(ap[mt][1], onesf, R[mt], 0, 0, 0);
        }
    }

    // epilogue: O/l, combined-head layout [b][l][h*64+d]; R holds row sums
    #pragma unroll
    for (int mt = 0; mt < 2; ++mt) {
        #pragma unroll
        for (int r = 0; r < 4; ++r) {
            float rsv = R[mt][r];
            float inv = (rsv > 0.f) ? 1.0f / rsv : 0.f;
            int qg = q0 + w * 32 + mt * 16 + quad * 4 + r;
            #pragma unroll
            for (int dt = 0; dt < 4; ++dt) {
                float ov = O[mt][dt][r] * inv;
                att[((size_t)b * 2048 + qg) * 1024 + h * 64 + dt * 16 + col] = (bf16)ov;
            }
        }
    }
}

extern "C" void kernel_launch(void* const* d_in, const int* in_sizes, int n_in,
                              void* d_out, int out_size, void* d_ws, size_t ws_size,
                              hipStream_t stream) {
    (void)in_sizes; (void)n_in; (void)out_size; (void)ws_size;
    const float* query = (const float*)d_in[0];
    const float* key_  = (const float*)d_in[1];
    const float* value = (const float*)d_in[2];
    const void*  mask  = d_in[3];
    const float* W_q = (const float*)d_in[4];
    const float* b_q = (const float*)d_in[5];
    const float* W_k = (const float*)d_in[6];
    const float* b_k = (const float*)d_in[7];
    const float* W_v = (const float*)d_in[8];
    const float* b_v = (const float*)d_in[9];
    const float* W_o = (const float*)d_in[10];
    const float* b_o = (const float*)d_in[11];

    char* ws = (char*)d_ws;
    bf16* Xq  = (bf16*)(ws + 0);
    bf16* Xk  = (bf16*)(ws + 8388608);
    bf16* Xv  = (bf16*)(ws + 16777216);
    bf16* Wtq = (bf16*)(ws + 25165824);
    bf16* Wtk = (bf16*)(ws + 27262976);
    bf16* Wtv = (bf16*)(ws + 29360128);
    bf16* Wto = (bf16*)(ws + 31457280);
    bf16* Qh  = (bf16*)(ws + 33554432);
    bf16* Kh  = (bf16*)(ws + 41943040);
    bf16* Vt  = (bf16*)(ws + 50331648);
    bf16* att = (bf16*)(ws + 58720256);
    unsigned long long* rmb = (unsigned long long*)(ws + 67633152);

    // prep: y=0..2 cvt fp32->bf16, y=3 wtrans (bx<1024) + mask->rmb (bx>=1024)
    prep_kernel<<<dim3(4096, 4), 256, 0, stream>>>(query, key_, value, Xq, Xk, Xv,
                                                   W_q, W_k, W_v, W_o,
                                                   Wtq, Wtk, Wtv, Wto,
                                                   (const unsigned int*)mask, rmb);

    qkv_kernel<<<dim3(256, 3), 256, 0, stream>>>(Xq, Xk, Xv, Wtq, Wtk, Wtv,
                                                 b_q, b_k, b_v, Qh, Kh, Vt);
    attn_kernel<<<dim3(32, 32), 128, 0, stream>>>(Qh, Kh, Vt, rmb, att);
    ogemm_kernel<<<512, 256, 0, stream>>>(att, Wto, b_o, (float*)d_out);
}